// Round 1
// 3207.335 us; speedup vs baseline: 1.0775x; 1.0775x over previous
//
#include <hip/hip_runtime.h>
#include <math.h>

// Problem constants (fixed by the reference)
#define DM 1024
#define SEQ 2048
#define BATCH 2
#define NHEAD 16
#define HDIM 64
#define NLAYER 8
#define FFDIM 4096
#define MROWS (BATCH*SEQ)    // 4096
#define QSTR 3072            // fused qkv row stride (shorts)

typedef __attribute__((ext_vector_type(8))) unsigned short short8;
typedef __attribute__((ext_vector_type(8))) __bf16 bf16x8;
typedef __attribute__((ext_vector_type(4))) float f32x4;

__device__ __forceinline__ float softplus_f(float x){
    return fmaxf(x, 0.0f) + log1pf(__expf(-fabsf(x)));
}

// fp32 -> bf16 round-to-nearest-even (finite inputs)
__device__ __forceinline__ unsigned short f2bf(float f){
    unsigned u = __builtin_bit_cast(unsigned, f);
    u += 0x7fffu + ((u >> 16) & 1u);
    return (unsigned short)(u >> 16);
}

// async global->LDS, 16B per lane; LDS dest = wave-uniform base + lane*16
__device__ __forceinline__ void gload_lds16(const void* g, void* l){
    __builtin_amdgcn_global_load_lds(
        (const __attribute__((address_space(1))) unsigned int*)g,
        (__attribute__((address_space(3))) unsigned int*)l, 16, 0, 0);
}

// ---------------------------------------------------------------------------
// Transpose-cast: src fp32 [K,N] row-major -> dst bf16 [N,K] row-major.
__global__ __launch_bounds__(256) void tcast_kernel(
    const float* __restrict__ src, unsigned short* __restrict__ dst, int K, int N)
{
    __shared__ float tile[32][33];
    const int bn = blockIdx.x * 32, bk = blockIdx.y * 32;
    const int tx = threadIdx.x & 31, ty = threadIdx.x >> 5;
    #pragma unroll
    for (int i = 0; i < 32; i += 8)
        tile[ty + i][tx] = src[(size_t)(bk + ty + i) * N + bn + tx];
    __syncthreads();
    #pragma unroll
    for (int i = 0; i < 32; i += 8)
        dst[(size_t)(bn + ty + i) * K + bk + tx] = f2bf(tile[tx][ty + i]);
}

// concat [bq | bkv] per layer into [NLAYER][3072] fp32
__global__ __launch_bounds__(256) void bias_concat_kernel(
    const float* __restrict__ bq, const float* __restrict__ bkv, float* __restrict__ dst)
{
    const int i = blockIdx.x * 256 + threadIdx.x;
    const int l = i / QSTR, c = i % QSTR;
    dst[i] = (c < DM) ? bq[l * DM + c] : bkv[l * 2 * DM + (c - DM)];
}

// ---------------------------------------------------------------------------
// Transpose the V third of qkv (bf16) into vt[b][h*64+d][s] (bf16).
// One 64x64 tile per block; all global accesses 128B-coalesced uint4.
__global__ __launch_bounds__(256) void vtrans_kernel(
    const unsigned short* __restrict__ qkv, unsigned short* __restrict__ vt)
{
    __shared__ unsigned short tile[64][72];
    const int b  = blockIdx.z;
    const int c0 = blockIdx.x * 64;   // over 1024 cols (h*64+d)
    const int s0 = blockIdx.y * 64;   // over SEQ
    const int r  = threadIdx.x >> 2;
    const int cq = (threadIdx.x & 3) * 16;
    {
        const unsigned short* src = qkv + (size_t)(b*SEQ + s0 + r) * QSTR + 2*DM + c0 + cq;
        *(uint4*)&tile[r][cq]     = *(const uint4*)(src);
        *(uint4*)&tile[r][cq + 8] = *(const uint4*)(src + 8);
    }
    __syncthreads();
    unsigned short tmp[16];
    #pragma unroll
    for (int j = 0; j < 16; j++) tmp[j] = tile[cq + j][r];
    unsigned short* dst = vt + (size_t)(b*DM + c0 + r) * SEQ + s0 + cq;
    *(uint4*)(dst)     = *(const uint4*)&tmp[0];
    *(uint4*)(dst + 8) = *(const uint4*)&tmp[8];
}

// ---------------------------------------------------------------------------
// LayerNorm: one block per row of 1024 floats. eps=1e-3. Output fp32 or bf16.
template<bool OUT_BF16>
__global__ __launch_bounds__(256) void ln_kernel(
    const float* __restrict__ x, const float* __restrict__ gamma,
    const float* __restrict__ beta, void* __restrict__ outv)
{
    const int row = blockIdx.x;
    const int t = threadIdx.x;
    const float4 v = ((const float4*)(x + (size_t)row * DM))[t];
    float s  = v.x + v.y + v.z + v.w;
    float s2 = v.x*v.x + v.y*v.y + v.z*v.z + v.w*v.w;
    #pragma unroll
    for (int off = 32; off > 0; off >>= 1){
        s  += __shfl_down(s,  off);
        s2 += __shfl_down(s2, off);
    }
    __shared__ float red[8];
    const int wid = t >> 6;
    if ((t & 63) == 0){ red[wid] = s; red[4 + wid] = s2; }
    __syncthreads();
    if (t == 0){
        red[0] = red[0] + red[1] + red[2] + red[3];
        red[4] = red[4] + red[5] + red[6] + red[7];
    }
    __syncthreads();
    const float mean = red[0] * (1.0f / DM);
    const float var  = red[4] * (1.0f / DM) - mean * mean;
    const float rstd = rsqrtf(var + 1e-3f);
    const float4 g  = ((const float4*)gamma)[t];
    const float4 bt = ((const float4*)beta)[t];
    float ox = (v.x - mean) * rstd * g.x + bt.x;
    float oy = (v.y - mean) * rstd * g.y + bt.y;
    float oz = (v.z - mean) * rstd * g.z + bt.z;
    float ow = (v.w - mean) * rstd * g.w + bt.w;
    if (OUT_BF16){
        ushort4 o = make_ushort4(f2bf(ox), f2bf(oy), f2bf(oz), f2bf(ow));
        *(ushort4*)((unsigned short*)outv + (size_t)row * DM + t*4) = o;
    } else {
        ((float4*)((float*)outv + (size_t)row * DM))[t] = make_float4(ox, oy, oz, ow);
    }
}

// ---------------------------------------------------------------------------
// bf16 MFMA GEMM (m97 structure): C[M,N] = A[M,K] @ Bt[N,K]^T + bias.
template<bool SOFTPLUS, bool RESIDUAL, bool OUT_BF16>
__global__ __launch_bounds__(256) void gemm_bf16_kernel(
    const unsigned short* __restrict__ A, const unsigned short* __restrict__ Bt,
    const float* __restrict__ bias, const float* __restrict__ resid,
    void* __restrict__ Cv, int N, int K)
{
    __shared__ __align__(16) unsigned short As[128 * 32];
    __shared__ __align__(16) unsigned short Bs[128 * 32];
    const int t = threadIdx.x;
    const int lane = t & 63, w = t >> 6;
    const int bm = blockIdx.y * 128, bn = blockIdx.x * 128;

    const int srow = lane >> 2;
    const int scol = (lane & 3) * 8;
    const unsigned short* a_g0 = A  + (size_t)(bm + w*32 + srow) * K + scol;
    const unsigned short* a_g1 = a_g0 + (size_t)16 * K;
    const unsigned short* b_g0 = Bt + (size_t)(bn + w*32 + srow) * K + scol;
    const unsigned short* b_g1 = b_g0 + (size_t)16 * K;
    unsigned short* a_l0 = &As[(w*32     ) * 32];
    unsigned short* a_l1 = &As[(w*32 + 16) * 32];
    unsigned short* b_l0 = &Bs[(w*32     ) * 32];
    unsigned short* b_l1 = &Bs[(w*32 + 16) * 32];

    const int wr = (w >> 1) * 64;
    const int wc = (w & 1) * 64;
    const int fm = lane & 15;
    const int fq = (lane >> 4) * 8;

    f32x4 acc[4][4] = {};

    for (int k0 = 0; k0 < K; k0 += 32){
        __syncthreads();
        gload_lds16(a_g0 + k0, a_l0);
        gload_lds16(a_g1 + k0, a_l1);
        gload_lds16(b_g0 + k0, b_l0);
        gload_lds16(b_g1 + k0, b_l1);
        __syncthreads();

        bf16x8 af[4], bfr[4];
        #pragma unroll
        for (int mi = 0; mi < 4; mi++)
            af[mi] = __builtin_bit_cast(bf16x8,
                *(const short8*)&As[(wr + mi*16 + fm) * 32 + fq]);
        #pragma unroll
        for (int ni = 0; ni < 4; ni++)
            bfr[ni] = __builtin_bit_cast(bf16x8,
                *(const short8*)&Bs[(wc + ni*16 + fm) * 32 + fq]);
        #pragma unroll
        for (int mi = 0; mi < 4; mi++)
            #pragma unroll
            for (int ni = 0; ni < 4; ni++)
                acc[mi][ni] = __builtin_amdgcn_mfma_f32_16x16x32_bf16(
                    af[mi], bfr[ni], acc[mi][ni], 0, 0, 0);
    }

    const int crow = (lane >> 4) * 4;
    const int ccol = lane & 15;
    #pragma unroll
    for (int mi = 0; mi < 4; mi++){
        #pragma unroll
        for (int r = 0; r < 4; r++){
            const size_t row = (size_t)bm + wr + mi*16 + crow + r;
            #pragma unroll
            for (int ni = 0; ni < 4; ni++){
                const int col = bn + wc + ni*16 + ccol;
                float v = acc[mi][ni][r] + bias[col];
                if (SOFTPLUS) v = softplus_f(v);
                if (RESIDUAL) v += resid[row * N + col];
                if (OUT_BF16) ((unsigned short*)Cv)[row * N + col] = f2bf(v);
                else          ((float*)Cv)[row * N + col] = v;
            }
        }
    }
}

// ---------------------------------------------------------------------------
// MFMA flash attention, ALiBi + causal. qkv bf16 [B*S, 3072]; vt = V^T
// (bf16 [b][h*64+d][s]); out bf16.
// Per block: 64 q-rows; wave w owns q-slice w*16..w*16+15.
// S^T = K·Q^T  (C-layout gives each lane 4 consecutive kpos for ONE q =>
// scalar m/l per lane, b64 P-writes directly in the PV A-operand layout).
// Softmax runs in exp2 domain (log2e folded into scale & ALiBi slope).
// Causal mask applied only on the diagonal tile (kt<qt is always in-range).
// Defer-max (THR=8): skip O-rescale when per-row max grew by <= 8.
// Block-id remap: co-resident blocks (dispatch ids stride 256 apart -> same
// CU at full residency) get qt = m and 31-m for both b, so every CU's four
// blocks total exactly 66 k-tile units (fixes the qt-aligned 1.9x tail).
__global__ __launch_bounds__(256, 4) void attn_kernel(
    const unsigned short* __restrict__ qkv,
    const unsigned short* __restrict__ vt,
    unsigned short* __restrict__ outg)
{
    __shared__ __align__(16) unsigned short Qs[64][72];
    __shared__ __align__(16) unsigned short Ks[64][72];
    __shared__ __align__(16) unsigned short Vt[64][72];
    __shared__ __align__(16) unsigned short Ps[64][72];

    const int L   = blockIdx.x + 32 * (blockIdx.y + 16 * blockIdx.z);
    const int rep = L >> 8, jj = L & 255;
    const int mm  = jj >> 4, h = jj & 15;
    const int b   = rep >> 1;
    const int qt  = (rep & 1) ? (31 - mm) : mm;

    const int t = threadIdx.x;
    const int lane = t & 63, w = t >> 6;
    const int g = lane >> 4, s = lane & 15;   // quad, sub-lane

    const size_t qrow0 = (size_t)(b * SEQ + qt * 64);
    const int srow = t >> 2, slc = t & 3;     // row-staging map (4 lanes/row)

    // --- stage Q tile (once) ---
    {
        const unsigned short* src = qkv + (qrow0 + srow) * QSTR + h*HDIM + slc*16;
        *(uint4*)&Qs[srow][slc*16]     = *(const uint4*)(src);
        *(uint4*)&Qs[srow][slc*16 + 8] = *(const uint4*)(src + 8);
    }
    __syncthreads();
    // Q fragments are block-constant: hoist out of the K-loop
    bf16x8 qf0 = __builtin_bit_cast(bf16x8, *(const short8*)&Qs[w*16 + s][g*8]);
    bf16x8 qf1 = __builtin_bit_cast(bf16x8, *(const short8*)&Qs[w*16 + s][32 + g*8]);

    const float LOG2E  = 1.4426950408889634f;
    const float qscale = 0.125f * LOG2E;
    const float slope  = exp2f(-0.5f * (float)(h + 1)) * LOG2E;  // ALiBi, log2 dom
    const int qi = qt*64 + w*16 + s;                  // this lane's q index
    float m_i = -1e30f, l_i = 0.0f;
    f32x4 accO[4] = {};

    const unsigned short* vbase = vt + (size_t)(b*DM + h*HDIM + srow) * SEQ;

    for (int kt = 0; kt <= qt; kt++){
        __syncthreads();   // prior PV done reading Ks/Vt before restage
        // stage K rows [kpos][d]
        {
            const unsigned short* src =
                qkv + (size_t)(b*SEQ + kt*64 + srow) * QSTR + DM + h*HDIM + slc*16;
            *(uint4*)&Ks[srow][slc*16]     = *(const uint4*)(src);
            *(uint4*)&Ks[srow][slc*16 + 8] = *(const uint4*)(src + 8);
        }
        // stage V^T rows [d][kpos] from the pre-transposed buffer (coalesced)
        {
            const unsigned short* src = vbase + kt*64 + slc*16;
            *(uint4*)&Vt[srow][slc*16]     = *(const uint4*)(src);
            *(uint4*)&Vt[srow][slc*16 + 8] = *(const uint4*)(src + 8);
        }
        __syncthreads();

        // --- S^T = K·Q^T : 4 kpos-tiles (mi), contraction d=64 in 2 chunks ---
        f32x4 sacc[4] = {};
        #pragma unroll
        for (int mi = 0; mi < 4; mi++){
            bf16x8 kf0 = __builtin_bit_cast(bf16x8, *(const short8*)&Ks[mi*16 + s][g*8]);
            bf16x8 kf1 = __builtin_bit_cast(bf16x8, *(const short8*)&Ks[mi*16 + s][32 + g*8]);
            sacc[mi] = __builtin_amdgcn_mfma_f32_16x16x32_bf16(kf0, qf0, sacc[mi], 0, 0, 0);
            sacc[mi] = __builtin_amdgcn_mfma_f32_16x16x32_bf16(kf1, qf1, sacc[mi], 0, 0, 0);
        }

        // --- scale + ALiBi (exp2 domain); lane holds 16 kpos for its q ---
        float sc[16];
        const float bb = slope * (float)(kt*64 - qi);
        #pragma unroll
        for (int mi = 0; mi < 4; mi++)
            #pragma unroll
            for (int r = 0; r < 4; r++)
                sc[mi*4 + r] = fmaf(sacc[mi][r], qscale,
                                    fmaf(slope, (float)(mi*16 + g*4 + r), bb));
        if (kt == qt){   // causal mask only needed on the diagonal tile
            #pragma unroll
            for (int mi = 0; mi < 4; mi++)
                #pragma unroll
                for (int r = 0; r < 4; r++)
                    if (mi*16 + g*4 + r > w*16 + s) sc[mi*4 + r] = -1e30f;
        }
        float mloc = sc[0];
        #pragma unroll
        for (int e = 1; e < 16; e++) mloc = fmaxf(mloc, sc[e]);
        // reduce over the 4 quads (lanes with same s): xor 16, 32
        mloc = fmaxf(mloc, __shfl_xor(mloc, 16));
        mloc = fmaxf(mloc, __shfl_xor(mloc, 32));

        float nm;
        if (__all(mloc - m_i <= 8.0f)){
            nm = m_i;                    // defer-max: P bounded by 2^8, skip rescale
        } else {
            nm = fmaxf(m_i, mloc);
            const float alpha = exp2f(m_i - nm);
            m_i = nm;
            float av[4];
            #pragma unroll
            for (int r = 0; r < 4; r++) av[r] = __shfl(alpha, g*4 + r);
            #pragma unroll
            for (int ni = 0; ni < 4; ni++)
                #pragma unroll
                for (int r = 0; r < 4; r++) accO[ni][r] *= av[r];
            l_i *= alpha;
        }

        float rsum = 0.0f;
        #pragma unroll
        for (int mi = 0; mi < 4; mi++){
            const float p0 = exp2f(sc[mi*4+0] - nm);
            const float p1 = exp2f(sc[mi*4+1] - nm);
            const float p2 = exp2f(sc[mi*4+2] - nm);
            const float p3 = exp2f(sc[mi*4+3] - nm);
            rsum += (p0 + p1) + (p2 + p3);
            // P write: 4 consecutive kpos for this q -> single b64
            *(ushort4*)&Ps[w*16 + s][mi*16 + g*4] =
                make_ushort4(f2bf(p0), f2bf(p1), f2bf(p2), f2bf(p3));
        }
        rsum += __shfl_xor(rsum, 16);
        rsum += __shfl_xor(rsum, 32);
        l_i += rsum;

        // --- O += P·V : A=Ps rows (own q-slice, same-wave data), B=Vt rows ---
        bf16x8 pf0 = __builtin_bit_cast(bf16x8, *(const short8*)&Ps[w*16 + s][g*8]);
        bf16x8 pf1 = __builtin_bit_cast(bf16x8, *(const short8*)&Ps[w*16 + s][32 + g*8]);
        #pragma unroll
        for (int ni = 0; ni < 4; ni++){
            bf16x8 vf0 = __builtin_bit_cast(bf16x8, *(const short8*)&Vt[ni*16 + s][g*8]);
            bf16x8 vf1 = __builtin_bit_cast(bf16x8, *(const short8*)&Vt[ni*16 + s][32 + g*8]);
            accO[ni] = __builtin_amdgcn_mfma_f32_16x16x32_bf16(pf0, vf0, accO[ni], 0, 0, 0);
            accO[ni] = __builtin_amdgcn_mfma_f32_16x16x32_bf16(pf1, vf1, accO[ni], 0, 0, 0);
        }
    }

    // epilogue: per-row 1/l broadcast, write bf16
    float lv[4];
    #pragma unroll
    for (int r = 0; r < 4; r++) lv[r] = 1.0f / __shfl(l_i, g*4 + r);
    #pragma unroll
    for (int ni = 0; ni < 4; ni++)
        #pragma unroll
        for (int r = 0; r < 4; r++)
            outg[(qrow0 + w*16 + g*4 + r) * DM + h*HDIM + ni*16 + s] =
                f2bf(accO[ni][r] * lv[r]);
}

// ---------------------------------------------------------------------------
extern "C" void kernel_launch(void* const* d_in, const int* in_sizes, int n_in,
                              void* d_out, int out_size, void* d_ws, size_t ws_size,
                              hipStream_t stream)
{
    (void)in_sizes; (void)n_in; (void)out_size; (void)ws_size;

    const float* x_in = (const float*)d_in[0];
    const float* fg   = (const float*)d_in[1];
    const float* fb   = (const float*)d_in[2];
    const float* wq   = (const float*)d_in[3];
    const float* bq   = (const float*)d_in[4];
    const float* wkv  = (const float*)d_in[5];
    const float* bkv  = (const float*)d_in[6];
    const float* wo   = (const float*)d_in[7];
    const float* bo   = (const float*)d_in[8];
    const float* w1   = (const float*)d_in[9];
    const float* b1   = (const float*)d_in[10];
    const float* w2   = (const float*)d_in[11];
    const float* b2   = (const float*)d_in[12];
    const float* attg = (const float*)d_in[13];
    const float* attb = (const float*)d_in[14];
    const float* ffng = (const float*)d_in[15];
    const float* ffnb = (const float*)d_in[16];

    float* x = (float*)d_out;                       // residual stream (fp32)

    char* wp = (char*)d_ws;
    unsigned short* qkvbuf = (unsigned short*)wp; wp += (size_t)MROWS*QSTR*2;   // 24 MB
    unsigned short* h1buf  = (unsigned short*)wp; wp += (size_t)MROWS*FFDIM*2;  // 32 MB
    unsigned short* hbuf   = (unsigned short*)wp; wp += (size_t)MROWS*DM*2;     //  8 MB
    unsigned short* attbuf = (unsigned short*)wp; wp += (size_t)MROWS*DM*2;     //  8 MB
    unsigned short* wt_qkv = (unsigned short*)wp; wp += (size_t)QSTR*DM*2;      //  6 MB
    unsigned short* wt_o   = (unsigned short*)wp; wp += (size_t)DM*DM*2;        //  2 MB
    unsigned short* wt_1   = (unsigned short*)wp; wp += (size_t)FFDIM*DM*2;     //  8 MB
    unsigned short* wt_2   = (unsigned short*)wp; wp += (size_t)DM*FFDIM*2;     //  8 MB
    float*          qkv_b  = (float*)wp;          wp += (size_t)NLAYER*QSTR*4;  // 96 KB

    // V^T scratch (8 MB) reuses the front of h1buf: h1buf is only live from
    // ffn1-write to ffn2-read, vt only from vtrans to attn -- disjoint.
    unsigned short* vtbuf = h1buf;

    hipMemcpyAsync(x, x_in, (size_t)MROWS*DM*sizeof(float),
                   hipMemcpyDeviceToDevice, stream);
    bias_concat_kernel<<<NLAYER*QSTR/256, 256, 0, stream>>>(bq, bkv, qkv_b);

    const dim3 blk(256);
    const dim3 g_qkv(QSTR/128,  MROWS/128);   // (24,32)
    const dim3 g_sq (DM/128,    MROWS/128);   // (8,32)
    const dim3 g_ff (FFDIM/128, MROWS/128);   // (32,32)
    const dim3 g_at (SEQ/64, NHEAD, BATCH);   // (32,16,2)
    const dim3 g_vt (DM/64, SEQ/64, BATCH);   // (16,32,2)

    for (int i = 0; i < NLAYER; i++){
        const float* wq_i  = wq  + (size_t)i*DM*DM;
        const float* wkv_i = wkv + (size_t)i*DM*2*DM;
        const float* wo_i  = wo  + (size_t)i*DM*DM;
        const float* bo_i  = bo  + (size_t)i*DM;
        const float* w1_i  = w1  + (size_t)i*DM*FFDIM;
        const float* b1_i  = b1  + (size_t)i*FFDIM;
        const float* w2_i  = w2  + (size_t)i*FFDIM*DM;
        const float* b2_i  = b2  + (size_t)i*DM;

        tcast_kernel<<<dim3(DM/32,    DM/32),    blk, 0, stream>>>(wq_i,  wt_qkv,         DM,    DM);
        tcast_kernel<<<dim3(2*DM/32,  DM/32),    blk, 0, stream>>>(wkv_i, wt_qkv + DM*DM, DM,    2*DM);
        tcast_kernel<<<dim3(DM/32,    DM/32),    blk, 0, stream>>>(wo_i,  wt_o,           DM,    DM);
        tcast_kernel<<<dim3(FFDIM/32, DM/32),    blk, 0, stream>>>(w1_i,  wt_1,           DM,    FFDIM);
        tcast_kernel<<<dim3(DM/32,    FFDIM/32), blk, 0, stream>>>(w2_i,  wt_2,           FFDIM, DM);

        // h = LN(x) -> bf16
        ln_kernel<true><<<MROWS, blk, 0, stream>>>(x, attg + (size_t)i*DM, attb + (size_t)i*DM, hbuf);
        // qkv = h @ [wq|wkv] + [bq|bkv] -> bf16
        gemm_bf16_kernel<false,false,true><<<g_qkv, blk, 0, stream>>>(
            hbuf, wt_qkv, qkv_b + (size_t)i*QSTR, nullptr, qkvbuf, QSTR, DM);
        // vt = V^T (once per layer; amortized over ~16.5 reads per V tile)
        vtrans_kernel<<<g_vt, blk, 0, stream>>>(qkvbuf, vtbuf);
        // att = flash_attention(qkv, vt) -> bf16
        attn_kernel<<<g_at, blk, 0, stream>>>(qkvbuf, vtbuf, attbuf);
        // x = x + att @ wo + bo
        gemm_bf16_kernel<false,true,false><<<g_sq, blk, 0, stream>>>(
            attbuf, wt_o, bo_i, x, x, DM, DM);
        // h = LN(x) -> bf16
        ln_kernel<true><<<MROWS, blk, 0, stream>>>(x, ffng + (size_t)i*DM, ffnb + (size_t)i*DM, hbuf);
        // h1 = softplus(h @ w1 + b1) -> bf16
        gemm_bf16_kernel<true,false,true><<<g_ff, blk, 0, stream>>>(
            hbuf, wt_1, b1_i, nullptr, h1buf, FFDIM, DM);
        // x = x + h1 @ w2 + b2
        gemm_bf16_kernel<false,true,false><<<g_sq, blk, 0, stream>>>(
            h1buf, wt_2, b2_i, x, x, DM, FFDIM);
    }
    // out = LN(x) fp32, in-place on d_out
    ln_kernel<false><<<MROWS, blk, 0, stream>>>(x, fg, fb, x);
}

// Round 2
// 2802.841 us; speedup vs baseline: 1.2330x; 1.1443x over previous
//
#include <hip/hip_runtime.h>
#include <math.h>

// Problem constants (fixed by the reference)
#define DM 1024
#define SEQ 2048
#define BATCH 2
#define NHEAD 16
#define HDIM 64
#define NLAYER 8
#define FFDIM 4096
#define MROWS (BATCH*SEQ)    // 4096
#define QSTR 3072            // fused qkv row stride (shorts)

typedef __attribute__((ext_vector_type(8))) unsigned short short8;
typedef __attribute__((ext_vector_type(8))) __bf16 bf16x8;
typedef __attribute__((ext_vector_type(4))) float f32x4;

// Fast softplus: log1pf (precise OCML call, ~100 VALU) -> v_exp + v_log
// (~7 VALU). |err| ~ 1e-5 abs, far below bf16 rounding of the output.
__device__ __forceinline__ float softplus_f(float x){
    const float t = __expf(-fabsf(x));
    return fmaxf(x, 0.0f) + __logf(1.0f + t);
}

// fp32 -> bf16 round-to-nearest-even (finite inputs)
__device__ __forceinline__ unsigned short f2bf(float f){
    unsigned u = __builtin_bit_cast(unsigned, f);
    u += 0x7fffu + ((u >> 16) & 1u);
    return (unsigned short)(u >> 16);
}

// async global->LDS, 16B per lane; LDS dest = wave-uniform base + lane*16
__device__ __forceinline__ void gload_lds16(const void* g, void* l){
    __builtin_amdgcn_global_load_lds(
        (const __attribute__((address_space(1))) unsigned int*)g,
        (__attribute__((address_space(3))) unsigned int*)l, 16, 0, 0);
}

// ---------------------------------------------------------------------------
// Transpose-cast: src fp32 [K,N] row-major -> dst bf16 [N,K] row-major.
__global__ __launch_bounds__(256) void tcast_kernel(
    const float* __restrict__ src, unsigned short* __restrict__ dst, int K, int N)
{
    __shared__ float tile[32][33];
    const int bn = blockIdx.x * 32, bk = blockIdx.y * 32;
    const int tx = threadIdx.x & 31, ty = threadIdx.x >> 5;
    #pragma unroll
    for (int i = 0; i < 32; i += 8)
        tile[ty + i][tx] = src[(size_t)(bk + ty + i) * N + bn + tx];
    __syncthreads();
    #pragma unroll
    for (int i = 0; i < 32; i += 8)
        dst[(size_t)(bn + ty + i) * K + bk + tx] = f2bf(tile[tx][ty + i]);
}

// concat [bq | bkv] per layer into [NLAYER][3072] fp32
__global__ __launch_bounds__(256) void bias_concat_kernel(
    const float* __restrict__ bq, const float* __restrict__ bkv, float* __restrict__ dst)
{
    const int i = blockIdx.x * 256 + threadIdx.x;
    const int l = i / QSTR, c = i % QSTR;
    dst[i] = (c < DM) ? bq[l * DM + c] : bkv[l * 2 * DM + (c - DM)];
}

// ---------------------------------------------------------------------------
// Transpose the V third of qkv (bf16) into vt[b][h*64+d][s] (bf16).
__global__ __launch_bounds__(256) void vtrans_kernel(
    const unsigned short* __restrict__ qkv, unsigned short* __restrict__ vt)
{
    __shared__ unsigned short tile[64][72];
    const int b  = blockIdx.z;
    const int c0 = blockIdx.x * 64;   // over 1024 cols (h*64+d)
    const int s0 = blockIdx.y * 64;   // over SEQ
    const int r  = threadIdx.x >> 2;
    const int cq = (threadIdx.x & 3) * 16;
    {
        const unsigned short* src = qkv + (size_t)(b*SEQ + s0 + r) * QSTR + 2*DM + c0 + cq;
        *(uint4*)&tile[r][cq]     = *(const uint4*)(src);
        *(uint4*)&tile[r][cq + 8] = *(const uint4*)(src + 8);
    }
    __syncthreads();
    unsigned short tmp[16];
    #pragma unroll
    for (int j = 0; j < 16; j++) tmp[j] = tile[cq + j][r];
    unsigned short* dst = vt + (size_t)(b*DM + c0 + r) * SEQ + s0 + cq;
    *(uint4*)(dst)     = *(const uint4*)&tmp[0];
    *(uint4*)(dst + 8) = *(const uint4*)&tmp[8];
}

// ---------------------------------------------------------------------------
// LayerNorm: one block per row of 1024 floats. eps=1e-3. Output fp32 or bf16.
template<bool OUT_BF16>
__global__ __launch_bounds__(256) void ln_kernel(
    const float* __restrict__ x, const float* __restrict__ gamma,
    const float* __restrict__ beta, void* __restrict__ outv)
{
    const int row = blockIdx.x;
    const int t = threadIdx.x;
    const float4 v = ((const float4*)(x + (size_t)row * DM))[t];
    float s  = v.x + v.y + v.z + v.w;
    float s2 = v.x*v.x + v.y*v.y + v.z*v.z + v.w*v.w;
    #pragma unroll
    for (int off = 32; off > 0; off >>= 1){
        s  += __shfl_down(s,  off);
        s2 += __shfl_down(s2, off);
    }
    __shared__ float red[8];
    const int wid = t >> 6;
    if ((t & 63) == 0){ red[wid] = s; red[4 + wid] = s2; }
    __syncthreads();
    if (t == 0){
        red[0] = red[0] + red[1] + red[2] + red[3];
        red[4] = red[4] + red[5] + red[6] + red[7];
    }
    __syncthreads();
    const float mean = red[0] * (1.0f / DM);
    const float var  = red[4] * (1.0f / DM) - mean * mean;
    const float rstd = rsqrtf(var + 1e-3f);
    const float4 g  = ((const float4*)gamma)[t];
    const float4 bt = ((const float4*)beta)[t];
    float ox = (v.x - mean) * rstd * g.x + bt.x;
    float oy = (v.y - mean) * rstd * g.y + bt.y;
    float oz = (v.z - mean) * rstd * g.z + bt.z;
    float ow = (v.w - mean) * rstd * g.w + bt.w;
    if (OUT_BF16){
        ushort4 o = make_ushort4(f2bf(ox), f2bf(oy), f2bf(oz), f2bf(ow));
        *(ushort4*)((unsigned short*)outv + (size_t)row * DM + t*4) = o;
    } else {
        ((float4*)((float*)outv + (size_t)row * DM))[t] = make_float4(ox, oy, oz, ow);
    }
}

// ---------------------------------------------------------------------------
// bf16 MFMA GEMM: C[M,N] = A[M,K] @ Bt[N,K]^T + bias.
// 2-phase double-buffered LDS (T3-minimum): issue next tile's
// global_load_lds BEFORE computing the current tile; single
// __syncthreads() (vmcnt(0)+barrier) per K-tile. This hides the load
// latency inside the block -- essential for the N=1024 GEMMs whose grid
// is only 1 block/CU (no co-resident-block overlap available).
// Requires K % 64 == 0 (K is 1024 or 4096 here).
template<bool SOFTPLUS, bool RESIDUAL, bool OUT_BF16>
__global__ __launch_bounds__(256) void gemm_bf16_kernel(
    const unsigned short* __restrict__ A, const unsigned short* __restrict__ Bt,
    const float* __restrict__ bias, const float* __restrict__ resid,
    void* __restrict__ Cv, int N, int K)
{
    __shared__ __align__(16) unsigned short As[2][128 * 32];
    __shared__ __align__(16) unsigned short Bs[2][128 * 32];
    const int t = threadIdx.x;
    const int lane = t & 63, w = t >> 6;
    const int bm = blockIdx.y * 128, bn = blockIdx.x * 128;

    const int srow = lane >> 2;
    const int scol = (lane & 3) * 8;
    const unsigned short* a_g0 = A  + (size_t)(bm + w*32 + srow) * K + scol;
    const unsigned short* a_g1 = a_g0 + (size_t)16 * K;
    const unsigned short* b_g0 = Bt + (size_t)(bn + w*32 + srow) * K + scol;
    const unsigned short* b_g1 = b_g0 + (size_t)16 * K;
    const int a_off0 = (w*32     ) * 32;   // wave-uniform LDS dest offsets
    const int a_off1 = (w*32 + 16) * 32;

    const int wr = (w >> 1) * 64;
    const int wc = (w & 1) * 64;
    const int fm = lane & 15;
    const int fq = (lane >> 4) * 8;

    f32x4 acc[4][4] = {};

#define STAGE(buf, k0)                                     \
    do {                                                   \
        gload_lds16(a_g0 + (k0), &As[buf][a_off0]);        \
        gload_lds16(a_g1 + (k0), &As[buf][a_off1]);        \
        gload_lds16(b_g0 + (k0), &Bs[buf][a_off0]);        \
        gload_lds16(b_g1 + (k0), &Bs[buf][a_off1]);        \
    } while (0)

#define COMPUTE(buf)                                                        \
    do {                                                                    \
        bf16x8 af[4], bfr[4];                                               \
        _Pragma("unroll")                                                   \
        for (int mi = 0; mi < 4; mi++)                                      \
            af[mi] = __builtin_bit_cast(bf16x8,                             \
                *(const short8*)&As[buf][(wr + mi*16 + fm) * 32 + fq]);     \
        _Pragma("unroll")                                                   \
        for (int ni = 0; ni < 4; ni++)                                      \
            bfr[ni] = __builtin_bit_cast(bf16x8,                            \
                *(const short8*)&Bs[buf][(wc + ni*16 + fm) * 32 + fq]);     \
        _Pragma("unroll")                                                   \
        for (int mi = 0; mi < 4; mi++)                                      \
            _Pragma("unroll")                                               \
            for (int ni = 0; ni < 4; ni++)                                  \
                acc[mi][ni] = __builtin_amdgcn_mfma_f32_16x16x32_bf16(      \
                    af[mi], bfr[ni], acc[mi][ni], 0, 0, 0);                 \
    } while (0)

    STAGE(0, 0);
    __syncthreads();                       // vmcnt(0) + barrier
    for (int k0 = 0; k0 < K; k0 += 64){
        STAGE(1, k0 + 32);                 // always in range: K % 64 == 0
        COMPUTE(0);
        __syncthreads();
        if (k0 + 64 < K) STAGE(0, k0 + 64);
        COMPUTE(1);
        __syncthreads();
    }
#undef STAGE
#undef COMPUTE

    const int crow = (lane >> 4) * 4;
    const int ccol = lane & 15;
    #pragma unroll
    for (int mi = 0; mi < 4; mi++){
        #pragma unroll
        for (int r = 0; r < 4; r++){
            const size_t row = (size_t)bm + wr + mi*16 + crow + r;
            #pragma unroll
            for (int ni = 0; ni < 4; ni++){
                const int col = bn + wc + ni*16 + ccol;
                float v = acc[mi][ni][r] + bias[col];
                if (SOFTPLUS) v = softplus_f(v);
                if (RESIDUAL) v += resid[row * N + col];
                if (OUT_BF16) ((unsigned short*)Cv)[row * N + col] = f2bf(v);
                else          ((float*)Cv)[row * N + col] = v;
            }
        }
    }
}

// ---------------------------------------------------------------------------
// MFMA flash attention, ALiBi + causal. qkv bf16 [B*S, 3072]; vt = V^T
// (bf16 [b][h*64+d][s]); out bf16.  (Unchanged from round 1.)
__global__ __launch_bounds__(256, 4) void attn_kernel(
    const unsigned short* __restrict__ qkv,
    const unsigned short* __restrict__ vt,
    unsigned short* __restrict__ outg)
{
    __shared__ __align__(16) unsigned short Qs[64][72];
    __shared__ __align__(16) unsigned short Ks[64][72];
    __shared__ __align__(16) unsigned short Vt[64][72];
    __shared__ __align__(16) unsigned short Ps[64][72];

    const int L   = blockIdx.x + 32 * (blockIdx.y + 16 * blockIdx.z);
    const int rep = L >> 8, jj = L & 255;
    const int mm  = jj >> 4, h = jj & 15;
    const int b   = rep >> 1;
    const int qt  = (rep & 1) ? (31 - mm) : mm;

    const int t = threadIdx.x;
    const int lane = t & 63, w = t >> 6;
    const int g = lane >> 4, s = lane & 15;   // quad, sub-lane

    const size_t qrow0 = (size_t)(b * SEQ + qt * 64);
    const int srow = t >> 2, slc = t & 3;     // row-staging map (4 lanes/row)

    // --- stage Q tile (once) ---
    {
        const unsigned short* src = qkv + (qrow0 + srow) * QSTR + h*HDIM + slc*16;
        *(uint4*)&Qs[srow][slc*16]     = *(const uint4*)(src);
        *(uint4*)&Qs[srow][slc*16 + 8] = *(const uint4*)(src + 8);
    }
    __syncthreads();
    bf16x8 qf0 = __builtin_bit_cast(bf16x8, *(const short8*)&Qs[w*16 + s][g*8]);
    bf16x8 qf1 = __builtin_bit_cast(bf16x8, *(const short8*)&Qs[w*16 + s][32 + g*8]);

    const float LOG2E  = 1.4426950408889634f;
    const float qscale = 0.125f * LOG2E;
    const float slope  = exp2f(-0.5f * (float)(h + 1)) * LOG2E;  // ALiBi, log2 dom
    const int qi = qt*64 + w*16 + s;                  // this lane's q index
    float m_i = -1e30f, l_i = 0.0f;
    f32x4 accO[4] = {};

    const unsigned short* vbase = vt + (size_t)(b*DM + h*HDIM + srow) * SEQ;

    for (int kt = 0; kt <= qt; kt++){
        __syncthreads();   // prior PV done reading Ks/Vt before restage
        {
            const unsigned short* src =
                qkv + (size_t)(b*SEQ + kt*64 + srow) * QSTR + DM + h*HDIM + slc*16;
            *(uint4*)&Ks[srow][slc*16]     = *(const uint4*)(src);
            *(uint4*)&Ks[srow][slc*16 + 8] = *(const uint4*)(src + 8);
        }
        {
            const unsigned short* src = vbase + kt*64 + slc*16;
            *(uint4*)&Vt[srow][slc*16]     = *(const uint4*)(src);
            *(uint4*)&Vt[srow][slc*16 + 8] = *(const uint4*)(src + 8);
        }
        __syncthreads();

        // --- S^T = K·Q^T ---
        f32x4 sacc[4] = {};
        #pragma unroll
        for (int mi = 0; mi < 4; mi++){
            bf16x8 kf0 = __builtin_bit_cast(bf16x8, *(const short8*)&Ks[mi*16 + s][g*8]);
            bf16x8 kf1 = __builtin_bit_cast(bf16x8, *(const short8*)&Ks[mi*16 + s][32 + g*8]);
            sacc[mi] = __builtin_amdgcn_mfma_f32_16x16x32_bf16(kf0, qf0, sacc[mi], 0, 0, 0);
            sacc[mi] = __builtin_amdgcn_mfma_f32_16x16x32_bf16(kf1, qf1, sacc[mi], 0, 0, 0);
        }

        // --- scale + ALiBi (exp2 domain) ---
        float sc[16];
        const float bb = slope * (float)(kt*64 - qi);
        #pragma unroll
        for (int mi = 0; mi < 4; mi++)
            #pragma unroll
            for (int r = 0; r < 4; r++)
                sc[mi*4 + r] = fmaf(sacc[mi][r], qscale,
                                    fmaf(slope, (float)(mi*16 + g*4 + r), bb));
        if (kt == qt){   // causal mask only needed on the diagonal tile
            #pragma unroll
            for (int mi = 0; mi < 4; mi++)
                #pragma unroll
                for (int r = 0; r < 4; r++)
                    if (mi*16 + g*4 + r > w*16 + s) sc[mi*4 + r] = -1e30f;
        }
        float mloc = sc[0];
        #pragma unroll
        for (int e = 1; e < 16; e++) mloc = fmaxf(mloc, sc[e]);
        mloc = fmaxf(mloc, __shfl_xor(mloc, 16));
        mloc = fmaxf(mloc, __shfl_xor(mloc, 32));

        float nm;
        if (__all(mloc - m_i <= 8.0f)){
            nm = m_i;                    // defer-max: P bounded by 2^8
        } else {
            nm = fmaxf(m_i, mloc);
            const float alpha = exp2f(m_i - nm);
            m_i = nm;
            float av[4];
            #pragma unroll
            for (int r = 0; r < 4; r++) av[r] = __shfl(alpha, g*4 + r);
            #pragma unroll
            for (int ni = 0; ni < 4; ni++)
                #pragma unroll
                for (int r = 0; r < 4; r++) accO[ni][r] *= av[r];
            l_i *= alpha;
        }

        float rsum = 0.0f;
        #pragma unroll
        for (int mi = 0; mi < 4; mi++){
            const float p0 = exp2f(sc[mi*4+0] - nm);
            const float p1 = exp2f(sc[mi*4+1] - nm);
            const float p2 = exp2f(sc[mi*4+2] - nm);
            const float p3 = exp2f(sc[mi*4+3] - nm);
            rsum += (p0 + p1) + (p2 + p3);
            *(ushort4*)&Ps[w*16 + s][mi*16 + g*4] =
                make_ushort4(f2bf(p0), f2bf(p1), f2bf(p2), f2bf(p3));
        }
        rsum += __shfl_xor(rsum, 16);
        rsum += __shfl_xor(rsum, 32);
        l_i += rsum;

        // --- O += P·V ---
        bf16x8 pf0 = __builtin_bit_cast(bf16x8, *(const short8*)&Ps[w*16 + s][g*8]);
        bf16x8 pf1 = __builtin_bit_cast(bf16x8, *(const short8*)&Ps[w*16 + s][32 + g*8]);
        #pragma unroll
        for (int ni = 0; ni < 4; ni++){
            bf16x8 vf0 = __builtin_bit_cast(bf16x8, *(const short8*)&Vt[ni*16 + s][g*8]);
            bf16x8 vf1 = __builtin_bit_cast(bf16x8, *(const short8*)&Vt[ni*16 + s][32 + g*8]);
            accO[ni] = __builtin_amdgcn_mfma_f32_16x16x32_bf16(pf0, vf0, accO[ni], 0, 0, 0);
            accO[ni] = __builtin_amdgcn_mfma_f32_16x16x32_bf16(pf1, vf1, accO[ni], 0, 0, 0);
        }
    }

    // epilogue: per-row 1/l broadcast, write bf16
    float lv[4];
    #pragma unroll
    for (int r = 0; r < 4; r++) lv[r] = 1.0f / __shfl(l_i, g*4 + r);
    #pragma unroll
    for (int ni = 0; ni < 4; ni++)
        #pragma unroll
        for (int r = 0; r < 4; r++)
            outg[(qrow0 + w*16 + g*4 + r) * DM + h*HDIM + ni*16 + s] =
                f2bf(accO[ni][r] * lv[r]);
}

// ---------------------------------------------------------------------------
extern "C" void kernel_launch(void* const* d_in, const int* in_sizes, int n_in,
                              void* d_out, int out_size, void* d_ws, size_t ws_size,
                              hipStream_t stream)
{
    (void)in_sizes; (void)n_in; (void)out_size; (void)ws_size;

    const float* x_in = (const float*)d_in[0];
    const float* fg   = (const float*)d_in[1];
    const float* fb   = (const float*)d_in[2];
    const float* wq   = (const float*)d_in[3];
    const float* bq   = (const float*)d_in[4];
    const float* wkv  = (const float*)d_in[5];
    const float* bkv  = (const float*)d_in[6];
    const float* wo   = (const float*)d_in[7];
    const float* bo   = (const float*)d_in[8];
    const float* w1   = (const float*)d_in[9];
    const float* b1   = (const float*)d_in[10];
    const float* w2   = (const float*)d_in[11];
    const float* b2   = (const float*)d_in[12];
    const float* attg = (const float*)d_in[13];
    const float* attb = (const float*)d_in[14];
    const float* ffng = (const float*)d_in[15];
    const float* ffnb = (const float*)d_in[16];

    float* x = (float*)d_out;                       // residual stream (fp32)

    char* wp = (char*)d_ws;
    unsigned short* qkvbuf = (unsigned short*)wp; wp += (size_t)MROWS*QSTR*2;   // 24 MB
    unsigned short* h1buf  = (unsigned short*)wp; wp += (size_t)MROWS*FFDIM*2;  // 32 MB
    unsigned short* hbuf   = (unsigned short*)wp; wp += (size_t)MROWS*DM*2;     //  8 MB
    unsigned short* attbuf = (unsigned short*)wp; wp += (size_t)MROWS*DM*2;     //  8 MB
    unsigned short* wt_qkv = (unsigned short*)wp; wp += (size_t)QSTR*DM*2;      //  6 MB
    unsigned short* wt_o   = (unsigned short*)wp; wp += (size_t)DM*DM*2;        //  2 MB
    unsigned short* wt_1   = (unsigned short*)wp; wp += (size_t)FFDIM*DM*2;     //  8 MB
    unsigned short* wt_2   = (unsigned short*)wp; wp += (size_t)DM*FFDIM*2;     //  8 MB
    float*          qkv_b  = (float*)wp;          wp += (size_t)NLAYER*QSTR*4;  // 96 KB

    // V^T scratch (8 MB) reuses the front of h1buf (disjoint live ranges).
    unsigned short* vtbuf = h1buf;

    hipMemcpyAsync(x, x_in, (size_t)MROWS*DM*sizeof(float),
                   hipMemcpyDeviceToDevice, stream);
    bias_concat_kernel<<<NLAYER*QSTR/256, 256, 0, stream>>>(bq, bkv, qkv_b);

    const dim3 blk(256);
    const dim3 g_qkv(QSTR/128,  MROWS/128);   // (24,32)
    const dim3 g_sq (DM/128,    MROWS/128);   // (8,32)
    const dim3 g_ff (FFDIM/128, MROWS/128);   // (32,32)
    const dim3 g_at (SEQ/64, NHEAD, BATCH);   // (32,16,2)
    const dim3 g_vt (DM/64, SEQ/64, BATCH);   // (16,32,2)

    for (int i = 0; i < NLAYER; i++){
        const float* wq_i  = wq  + (size_t)i*DM*DM;
        const float* wkv_i = wkv + (size_t)i*DM*2*DM;
        const float* wo_i  = wo  + (size_t)i*DM*DM;
        const float* bo_i  = bo  + (size_t)i*DM;
        const float* w1_i  = w1  + (size_t)i*DM*FFDIM;
        const float* b1_i  = b1  + (size_t)i*FFDIM;
        const float* w2_i  = w2  + (size_t)i*FFDIM*DM;
        const float* b2_i  = b2  + (size_t)i*DM;

        tcast_kernel<<<dim3(DM/32,    DM/32),    blk, 0, stream>>>(wq_i,  wt_qkv,         DM,    DM);
        tcast_kernel<<<dim3(2*DM/32,  DM/32),    blk, 0, stream>>>(wkv_i, wt_qkv + DM*DM, DM,    2*DM);
        tcast_kernel<<<dim3(DM/32,    DM/32),    blk, 0, stream>>>(wo_i,  wt_o,           DM,    DM);
        tcast_kernel<<<dim3(FFDIM/32, DM/32),    blk, 0, stream>>>(w1_i,  wt_1,           DM,    FFDIM);
        tcast_kernel<<<dim3(DM/32,    FFDIM/32), blk, 0, stream>>>(w2_i,  wt_2,           FFDIM, DM);

        // h = LN(x) -> bf16
        ln_kernel<true><<<MROWS, blk, 0, stream>>>(x, attg + (size_t)i*DM, attb + (size_t)i*DM, hbuf);
        // qkv = h @ [wq|wkv] + [bq|bkv] -> bf16
        gemm_bf16_kernel<false,false,true><<<g_qkv, blk, 0, stream>>>(
            hbuf, wt_qkv, qkv_b + (size_t)i*QSTR, nullptr, qkvbuf, QSTR, DM);
        // vt = V^T (once per layer)
        vtrans_kernel<<<g_vt, blk, 0, stream>>>(qkvbuf, vtbuf);
        // att = flash_attention(qkv, vt) -> bf16
        attn_kernel<<<g_at, blk, 0, stream>>>(qkvbuf, vtbuf, attbuf);
        // x = x + att @ wo + bo
        gemm_bf16_kernel<false,true,false><<<g_sq, blk, 0, stream>>>(
            attbuf, wt_o, bo_i, x, x, DM, DM);
        // h = LN(x) -> bf16
        ln_kernel<true><<<MROWS, blk, 0, stream>>>(x, ffng + (size_t)i*DM, ffnb + (size_t)i*DM, hbuf);
        // h1 = softplus(h @ w1 + b1) -> bf16
        gemm_bf16_kernel<true,false,true><<<g_ff, blk, 0, stream>>>(
            hbuf, wt_1, b1_i, nullptr, h1buf, FFDIM, DM);
        // x = x + h1 @ w2 + b2
        gemm_bf16_kernel<false,true,false><<<g_sq, blk, 0, stream>>>(
            h1buf, wt_2, b2_i, x, x, DM, FFDIM);
    }
    // out = LN(x) fp32, in-place on d_out
    ln_kernel<false><<<MROWS, blk, 0, stream>>>(x, fg, fb, x);
}

// Round 3
// 2267.972 us; speedup vs baseline: 1.5237x; 1.2358x over previous
//
#include <hip/hip_runtime.h>
#include <math.h>

// Problem constants (fixed by the reference)
#define DM 1024
#define SEQ 2048
#define BATCH 2
#define NHEAD 16
#define HDIM 64
#define NLAYER 8
#define FFDIM 4096
#define MROWS (BATCH*SEQ)    // 4096
#define QSTR 3072            // fused qkv row stride (shorts)

typedef __attribute__((ext_vector_type(8))) unsigned short short8;
typedef __attribute__((ext_vector_type(8))) __bf16 bf16x8;
typedef __attribute__((ext_vector_type(4))) float f32x4;

// Fast softplus: hardware v_exp + v_log (~7 VALU), |err| ~1e-5 abs.
__device__ __forceinline__ float softplus_f(float x){
    const float t = __expf(-fabsf(x));
    return fmaxf(x, 0.0f) + __logf(1.0f + t);
}

// fp32 -> bf16 round-to-nearest-even (finite inputs)
__device__ __forceinline__ unsigned short f2bf(float f){
    unsigned u = __builtin_bit_cast(unsigned, f);
    u += 0x7fffu + ((u >> 16) & 1u);
    return (unsigned short)(u >> 16);
}

// async global->LDS, 16B per lane; LDS dest = wave-uniform base + lane*16
__device__ __forceinline__ void gload_lds16(const void* g, void* l){
    __builtin_amdgcn_global_load_lds(
        (const __attribute__((address_space(1))) unsigned int*)g,
        (__attribute__((address_space(3))) unsigned int*)l, 16, 0, 0);
}

// ---------------------------------------------------------------------------
// Transpose-cast: src fp32 [K,N] row-major -> dst bf16 [N,K] row-major.
__global__ __launch_bounds__(256) void tcast_kernel(
    const float* __restrict__ src, unsigned short* __restrict__ dst, int K, int N)
{
    __shared__ float tile[32][33];
    const int bn = blockIdx.x * 32, bk = blockIdx.y * 32;
    const int tx = threadIdx.x & 31, ty = threadIdx.x >> 5;
    #pragma unroll
    for (int i = 0; i < 32; i += 8)
        tile[ty + i][tx] = src[(size_t)(bk + ty + i) * N + bn + tx];
    __syncthreads();
    #pragma unroll
    for (int i = 0; i < 32; i += 8)
        dst[(size_t)(bn + ty + i) * K + bk + tx] = f2bf(tile[tx][ty + i]);
}

// concat [bq | bkv] per layer into [NLAYER][3072] fp32
__global__ __launch_bounds__(256) void bias_concat_kernel(
    const float* __restrict__ bq, const float* __restrict__ bkv, float* __restrict__ dst)
{
    const int i = blockIdx.x * 256 + threadIdx.x;
    const int l = i / QSTR, c = i % QSTR;
    dst[i] = (c < DM) ? bq[l * DM + c] : bkv[l * 2 * DM + (c - DM)];
}

// ---------------------------------------------------------------------------
// Transpose the V third of qkv (bf16) into vt[b][h*64+d][s] (bf16).
__global__ __launch_bounds__(256) void vtrans_kernel(
    const unsigned short* __restrict__ qkv, unsigned short* __restrict__ vt)
{
    __shared__ unsigned short tile[64][72];
    const int b  = blockIdx.z;
    const int c0 = blockIdx.x * 64;   // over 1024 cols (h*64+d)
    const int s0 = blockIdx.y * 64;   // over SEQ
    const int r  = threadIdx.x >> 2;
    const int cq = (threadIdx.x & 3) * 16;
    {
        const unsigned short* src = qkv + (size_t)(b*SEQ + s0 + r) * QSTR + 2*DM + c0 + cq;
        *(uint4*)&tile[r][cq]     = *(const uint4*)(src);
        *(uint4*)&tile[r][cq + 8] = *(const uint4*)(src + 8);
    }
    __syncthreads();
    unsigned short tmp[16];
    #pragma unroll
    for (int j = 0; j < 16; j++) tmp[j] = tile[cq + j][r];
    unsigned short* dst = vt + (size_t)(b*DM + c0 + r) * SEQ + s0 + cq;
    *(uint4*)(dst)     = *(const uint4*)&tmp[0];
    *(uint4*)(dst + 8) = *(const uint4*)&tmp[8];
}

// ---------------------------------------------------------------------------
// LayerNorm: one block per row of 1024 floats. eps=1e-3. Output fp32 or bf16.
template<bool OUT_BF16>
__global__ __launch_bounds__(256) void ln_kernel(
    const float* __restrict__ x, const float* __restrict__ gamma,
    const float* __restrict__ beta, void* __restrict__ outv)
{
    const int row = blockIdx.x;
    const int t = threadIdx.x;
    const float4 v = ((const float4*)(x + (size_t)row * DM))[t];
    float s  = v.x + v.y + v.z + v.w;
    float s2 = v.x*v.x + v.y*v.y + v.z*v.z + v.w*v.w;
    #pragma unroll
    for (int off = 32; off > 0; off >>= 1){
        s  += __shfl_down(s,  off);
        s2 += __shfl_down(s2, off);
    }
    __shared__ float red[8];
    const int wid = t >> 6;
    if ((t & 63) == 0){ red[wid] = s; red[4 + wid] = s2; }
    __syncthreads();
    if (t == 0){
        red[0] = red[0] + red[1] + red[2] + red[3];
        red[4] = red[4] + red[5] + red[6] + red[7];
    }
    __syncthreads();
    const float mean = red[0] * (1.0f / DM);
    const float var  = red[4] * (1.0f / DM) - mean * mean;
    const float rstd = rsqrtf(var + 1e-3f);
    const float4 g  = ((const float4*)gamma)[t];
    const float4 bt = ((const float4*)beta)[t];
    float ox = (v.x - mean) * rstd * g.x + bt.x;
    float oy = (v.y - mean) * rstd * g.y + bt.y;
    float oz = (v.z - mean) * rstd * g.z + bt.z;
    float ow = (v.w - mean) * rstd * g.w + bt.w;
    if (OUT_BF16){
        ushort4 o = make_ushort4(f2bf(ox), f2bf(oy), f2bf(oz), f2bf(ow));
        *(ushort4*)((unsigned short*)outv + (size_t)row * DM + t*4) = o;
    } else {
        ((float4*)((float*)outv + (size_t)row * DM))[t] = make_float4(ox, oy, oz, ow);
    }
}

// ---------------------------------------------------------------------------
// bf16 MFMA GEMM: C[M,N] = A[M,K] @ Bt[N,K]^T + bias.
// Counted-vmcnt pipeline (T3/T4 minimum): BK=64, double-buffered LDS (64 KB),
// raw s_barrier + s_waitcnt vmcnt(8) -- one 8-load stage group stays in
// flight across ~2 iterations (never drained to 0 in the loop). Essential
// for the N=1024 GEMMs (grid = 256 blocks = 1 wave/SIMD: zero TLP, all
// latency must be hidden by the pipeline itself).
// LDS bank-swizzle via pre-swizzled GLOBAL source (linear gload_lds dest) +
// identical XOR on the ds_read slot (rule-21-correct involution).
// T1 XCD-chunked block swizzle: each XCD gets a contiguous row-chunk ->
// A-panels live in its private L2 (all grids here are %8 == 0).
// Requires K % 64 == 0 and K/64 >= 2 (K is 1024 or 4096 here).
template<bool SOFTPLUS, bool RESIDUAL, bool OUT_BF16>
__global__ __launch_bounds__(256, 2) void gemm_bf16_kernel(
    const unsigned short* __restrict__ A, const unsigned short* __restrict__ Bt,
    const float* __restrict__ bias, const float* __restrict__ resid,
    void* __restrict__ Cv, int N, int K)
{
    __shared__ __align__(16) unsigned short As[2][128 * 64];
    __shared__ __align__(16) unsigned short Bs[2][128 * 64];
    const int t = threadIdx.x;
    const int lane = t & 63, w = t >> 6;

    // XCD-chunked swizzle: hardware round-robins consecutive ids over 8 XCDs;
    // remap so ids sharing an XCD cover a contiguous tile-row chunk.
    const int gx = gridDim.x;
    const int nwg = gx * gridDim.y;
    int bid = blockIdx.x + gx * blockIdx.y;
    bid = (bid & 7) * (nwg >> 3) + (bid >> 3);
    const int bm = (bid / gx) * 128, bn = (bid % gx) * 128;

    // Staging geometry: lane covers (row = j*32 + w*8 + (l>>3), slot = l&7),
    // 16B per lane, 8 gload_lds16 per 128x64 A+B stage.
    // Source slot pre-swizzled: LDS[row][slot] holds G[row][slot ^ (row&7)],
    // and row&7 == l>>3 for every j (j*32, w*8 are multiples of 8).
    const int srow  = w*8 + (lane >> 3);
    const int sslot = (lane & 7) ^ (lane >> 3);
    const unsigned short* a_g = A  + (size_t)(bm + srow) * K + sslot * 8;
    const unsigned short* b_g = Bt + (size_t)(bn + srow) * K + sslot * 8;

    const int wr = (w >> 1) * 64;
    const int wc = (w & 1) * 64;
    const int fm = lane & 15;
    const int q  = lane >> 4;
    const int f7 = fm & 7;

    f32x4 acc[4][4] = {};
    const int ntile = K >> 6;

#define STAGE(buf, k0)                                                      \
    do {                                                                    \
        _Pragma("unroll")                                                   \
        for (int j = 0; j < 4; j++){                                        \
            gload_lds16(a_g + (size_t)(j*32)*K + (k0), &As[buf][(j*32 + w*8)*64]); \
            gload_lds16(b_g + (size_t)(j*32)*K + (k0), &Bs[buf][(j*32 + w*8)*64]); \
        }                                                                   \
    } while (0)

    // fragment ds_read: G-slot s = (kk>>3)+q for row r -> LDS slot s^(r&7)
#define LOADFRAGS(buf)                                                      \
    _Pragma("unroll")                                                       \
    for (int kk2 = 0; kk2 < 2; kk2++){                                      \
        _Pragma("unroll")                                                   \
        for (int mi = 0; mi < 4; mi++)                                      \
            af[kk2][mi] = __builtin_bit_cast(bf16x8, *(const short8*)       \
                &As[buf][(wr + mi*16 + fm)*64 + (((kk2*4 + q) ^ f7) << 3)]);\
        _Pragma("unroll")                                                   \
        for (int ni = 0; ni < 4; ni++)                                      \
            bfm[kk2][ni] = __builtin_bit_cast(bf16x8, *(const short8*)      \
                &Bs[buf][(wc + ni*16 + fm)*64 + (((kk2*4 + q) ^ f7) << 3)]);\
    }

#define MFMAS()                                                             \
    _Pragma("unroll")                                                       \
    for (int kk2 = 0; kk2 < 2; kk2++)                                       \
        _Pragma("unroll")                                                   \
        for (int mi = 0; mi < 4; mi++)                                      \
            _Pragma("unroll")                                               \
            for (int ni = 0; ni < 4; ni++)                                  \
                acc[mi][ni] = __builtin_amdgcn_mfma_f32_16x16x32_bf16(      \
                    af[kk2][mi], bfm[kk2][ni], acc[mi][ni], 0, 0, 0);

    // prologue: two stage groups in flight (16 loads)
    STAGE(0, 0);
    STAGE(1, 64);

    int cur = 0;
    for (int td = 0; td < ntile - 1; ++td){
        asm volatile("s_waitcnt vmcnt(8)" ::: "memory");   // tile td landed
        __builtin_amdgcn_s_barrier();
        bf16x8 af[2][4], bfm[2][4];
        LOADFRAGS(cur);
        asm volatile("s_waitcnt lgkmcnt(0)" ::: "memory"); // my reads drained
        __builtin_amdgcn_s_barrier();                      // all waves done reading
        if (td + 2 < ntile) STAGE(cur, (td + 2) * 64);     // overwrite is now safe
        MFMAS();
        cur ^= 1;
    }
    // tail tile: drain everything
    {
        asm volatile("s_waitcnt vmcnt(0)" ::: "memory");
        __builtin_amdgcn_s_barrier();
        bf16x8 af[2][4], bfm[2][4];
        LOADFRAGS(cur);
        MFMAS();
    }
#undef STAGE
#undef LOADFRAGS
#undef MFMAS

    const int crow = (lane >> 4) * 4;
    const int ccol = lane & 15;
    #pragma unroll
    for (int mi = 0; mi < 4; mi++){
        #pragma unroll
        for (int r = 0; r < 4; r++){
            const size_t row = (size_t)bm + wr + mi*16 + crow + r;
            #pragma unroll
            for (int ni = 0; ni < 4; ni++){
                const int col = bn + wc + ni*16 + ccol;
                float v = acc[mi][ni][r] + bias[col];
                if (SOFTPLUS) v = softplus_f(v);
                if (RESIDUAL) v += resid[row * N + col];
                if (OUT_BF16) ((unsigned short*)Cv)[row * N + col] = f2bf(v);
                else          ((float*)Cv)[row * N + col] = v;
            }
        }
    }
}

// ---------------------------------------------------------------------------
// MFMA flash attention, ALiBi + causal. (Unchanged from round 2.)
__global__ __launch_bounds__(256, 4) void attn_kernel(
    const unsigned short* __restrict__ qkv,
    const unsigned short* __restrict__ vt,
    unsigned short* __restrict__ outg)
{
    __shared__ __align__(16) unsigned short Qs[64][72];
    __shared__ __align__(16) unsigned short Ks[64][72];
    __shared__ __align__(16) unsigned short Vt[64][72];
    __shared__ __align__(16) unsigned short Ps[64][72];

    const int L   = blockIdx.x + 32 * (blockIdx.y + 16 * blockIdx.z);
    const int rep = L >> 8, jj = L & 255;
    const int mm  = jj >> 4, h = jj & 15;
    const int b   = rep >> 1;
    const int qt  = (rep & 1) ? (31 - mm) : mm;

    const int t = threadIdx.x;
    const int lane = t & 63, w = t >> 6;
    const int g = lane >> 4, s = lane & 15;   // quad, sub-lane

    const size_t qrow0 = (size_t)(b * SEQ + qt * 64);
    const int srow = t >> 2, slc = t & 3;     // row-staging map (4 lanes/row)

    {
        const unsigned short* src = qkv + (qrow0 + srow) * QSTR + h*HDIM + slc*16;
        *(uint4*)&Qs[srow][slc*16]     = *(const uint4*)(src);
        *(uint4*)&Qs[srow][slc*16 + 8] = *(const uint4*)(src + 8);
    }
    __syncthreads();
    bf16x8 qf0 = __builtin_bit_cast(bf16x8, *(const short8*)&Qs[w*16 + s][g*8]);
    bf16x8 qf1 = __builtin_bit_cast(bf16x8, *(const short8*)&Qs[w*16 + s][32 + g*8]);

    const float LOG2E  = 1.4426950408889634f;
    const float qscale = 0.125f * LOG2E;
    const float slope  = exp2f(-0.5f * (float)(h + 1)) * LOG2E;  // ALiBi, log2 dom
    const int qi = qt*64 + w*16 + s;                  // this lane's q index
    float m_i = -1e30f, l_i = 0.0f;
    f32x4 accO[4] = {};

    const unsigned short* vbase = vt + (size_t)(b*DM + h*HDIM + srow) * SEQ;

    for (int kt = 0; kt <= qt; kt++){
        __syncthreads();   // prior PV done reading Ks/Vt before restage
        {
            const unsigned short* src =
                qkv + (size_t)(b*SEQ + kt*64 + srow) * QSTR + DM + h*HDIM + slc*16;
            *(uint4*)&Ks[srow][slc*16]     = *(const uint4*)(src);
            *(uint4*)&Ks[srow][slc*16 + 8] = *(const uint4*)(src + 8);
        }
        {
            const unsigned short* src = vbase + kt*64 + slc*16;
            *(uint4*)&Vt[srow][slc*16]     = *(const uint4*)(src);
            *(uint4*)&Vt[srow][slc*16 + 8] = *(const uint4*)(src + 8);
        }
        __syncthreads();

        // --- S^T = K·Q^T ---
        f32x4 sacc[4] = {};
        #pragma unroll
        for (int mi = 0; mi < 4; mi++){
            bf16x8 kf0 = __builtin_bit_cast(bf16x8, *(const short8*)&Ks[mi*16 + s][g*8]);
            bf16x8 kf1 = __builtin_bit_cast(bf16x8, *(const short8*)&Ks[mi*16 + s][32 + g*8]);
            sacc[mi] = __builtin_amdgcn_mfma_f32_16x16x32_bf16(kf0, qf0, sacc[mi], 0, 0, 0);
            sacc[mi] = __builtin_amdgcn_mfma_f32_16x16x32_bf16(kf1, qf1, sacc[mi], 0, 0, 0);
        }

        // --- scale + ALiBi (exp2 domain) ---
        float sc[16];
        const float bb = slope * (float)(kt*64 - qi);
        #pragma unroll
        for (int mi = 0; mi < 4; mi++)
            #pragma unroll
            for (int r = 0; r < 4; r++)
                sc[mi*4 + r] = fmaf(sacc[mi][r], qscale,
                                    fmaf(slope, (float)(mi*16 + g*4 + r), bb));
        if (kt == qt){   // causal mask only needed on the diagonal tile
            #pragma unroll
            for (int mi = 0; mi < 4; mi++)
                #pragma unroll
                for (int r = 0; r < 4; r++)
                    if (mi*16 + g*4 + r > w*16 + s) sc[mi*4 + r] = -1e30f;
        }
        float mloc = sc[0];
        #pragma unroll
        for (int e = 1; e < 16; e++) mloc = fmaxf(mloc, sc[e]);
        mloc = fmaxf(mloc, __shfl_xor(mloc, 16));
        mloc = fmaxf(mloc, __shfl_xor(mloc, 32));

        float nm;
        if (__all(mloc - m_i <= 8.0f)){
            nm = m_i;                    // defer-max: P bounded by 2^8
        } else {
            nm = fmaxf(m_i, mloc);
            const float alpha = exp2f(m_i - nm);
            m_i = nm;
            float av[4];
            #pragma unroll
            for (int r = 0; r < 4; r++) av[r] = __shfl(alpha, g*4 + r);
            #pragma unroll
            for (int ni = 0; ni < 4; ni++)
                #pragma unroll
                for (int r = 0; r < 4; r++) accO[ni][r] *= av[r];
            l_i *= alpha;
        }

        float rsum = 0.0f;
        #pragma unroll
        for (int mi = 0; mi < 4; mi++){
            const float p0 = exp2f(sc[mi*4+0] - nm);
            const float p1 = exp2f(sc[mi*4+1] - nm);
            const float p2 = exp2f(sc[mi*4+2] - nm);
            const float p3 = exp2f(sc[mi*4+3] - nm);
            rsum += (p0 + p1) + (p2 + p3);
            *(ushort4*)&Ps[w*16 + s][mi*16 + g*4] =
                make_ushort4(f2bf(p0), f2bf(p1), f2bf(p2), f2bf(p3));
        }
        rsum += __shfl_xor(rsum, 16);
        rsum += __shfl_xor(rsum, 32);
        l_i += rsum;

        // --- O += P·V ---
        bf16x8 pf0 = __builtin_bit_cast(bf16x8, *(const short8*)&Ps[w*16 + s][g*8]);
        bf16x8 pf1 = __builtin_bit_cast(bf16x8, *(const short8*)&Ps[w*16 + s][32 + g*8]);
        #pragma unroll
        for (int ni = 0; ni < 4; ni++){
            bf16x8 vf0 = __builtin_bit_cast(bf16x8, *(const short8*)&Vt[ni*16 + s][g*8]);
            bf16x8 vf1 = __builtin_bit_cast(bf16x8, *(const short8*)&Vt[ni*16 + s][32 + g*8]);
            accO[ni] = __builtin_amdgcn_mfma_f32_16x16x32_bf16(pf0, vf0, accO[ni], 0, 0, 0);
            accO[ni] = __builtin_amdgcn_mfma_f32_16x16x32_bf16(pf1, vf1, accO[ni], 0, 0, 0);
        }
    }

    // epilogue: per-row 1/l broadcast, write bf16
    float lv[4];
    #pragma unroll
    for (int r = 0; r < 4; r++) lv[r] = 1.0f / __shfl(l_i, g*4 + r);
    #pragma unroll
    for (int ni = 0; ni < 4; ni++)
        #pragma unroll
        for (int r = 0; r < 4; r++)
            outg[(qrow0 + w*16 + g*4 + r) * DM + h*HDIM + ni*16 + s] =
                f2bf(accO[ni][r] * lv[r]);
}

// ---------------------------------------------------------------------------
extern "C" void kernel_launch(void* const* d_in, const int* in_sizes, int n_in,
                              void* d_out, int out_size, void* d_ws, size_t ws_size,
                              hipStream_t stream)
{
    (void)in_sizes; (void)n_in; (void)out_size; (void)ws_size;

    const float* x_in = (const float*)d_in[0];
    const float* fg   = (const float*)d_in[1];
    const float* fb   = (const float*)d_in[2];
    const float* wq   = (const float*)d_in[3];
    const float* bq   = (const float*)d_in[4];
    const float* wkv  = (const float*)d_in[5];
    const float* bkv  = (const float*)d_in[6];
    const float* wo   = (const float*)d_in[7];
    const float* bo   = (const float*)d_in[8];
    const float* w1   = (const float*)d_in[9];
    const float* b1   = (const float*)d_in[10];
    const float* w2   = (const float*)d_in[11];
    const float* b2   = (const float*)d_in[12];
    const float* attg = (const float*)d_in[13];
    const float* attb = (const float*)d_in[14];
    const float* ffng = (const float*)d_in[15];
    const float* ffnb = (const float*)d_in[16];

    float* x = (float*)d_out;                       // residual stream (fp32)

    char* wp = (char*)d_ws;
    unsigned short* qkvbuf = (unsigned short*)wp; wp += (size_t)MROWS*QSTR*2;   // 24 MB
    unsigned short* h1buf  = (unsigned short*)wp; wp += (size_t)MROWS*FFDIM*2;  // 32 MB
    unsigned short* hbuf   = (unsigned short*)wp; wp += (size_t)MROWS*DM*2;     //  8 MB
    unsigned short* attbuf = (unsigned short*)wp; wp += (size_t)MROWS*DM*2;     //  8 MB
    unsigned short* wt_qkv = (unsigned short*)wp; wp += (size_t)QSTR*DM*2;      //  6 MB
    unsigned short* wt_o   = (unsigned short*)wp; wp += (size_t)DM*DM*2;        //  2 MB
    unsigned short* wt_1   = (unsigned short*)wp; wp += (size_t)FFDIM*DM*2;     //  8 MB
    unsigned short* wt_2   = (unsigned short*)wp; wp += (size_t)DM*FFDIM*2;     //  8 MB
    float*          qkv_b  = (float*)wp;          wp += (size_t)NLAYER*QSTR*4;  // 96 KB

    // V^T scratch (8 MB) reuses the front of h1buf (disjoint live ranges).
    unsigned short* vtbuf = h1buf;

    hipMemcpyAsync(x, x_in, (size_t)MROWS*DM*sizeof(float),
                   hipMemcpyDeviceToDevice, stream);
    bias_concat_kernel<<<NLAYER*QSTR/256, 256, 0, stream>>>(bq, bkv, qkv_b);

    const dim3 blk(256);
    const dim3 g_qkv(QSTR/128,  MROWS/128);   // (24,32)
    const dim3 g_sq (DM/128,    MROWS/128);   // (8,32)
    const dim3 g_ff (FFDIM/128, MROWS/128);   // (32,32)
    const dim3 g_at (SEQ/64, NHEAD, BATCH);   // (32,16,2)
    const dim3 g_vt (DM/64, SEQ/64, BATCH);   // (16,32,2)

    for (int i = 0; i < NLAYER; i++){
        const float* wq_i  = wq  + (size_t)i*DM*DM;
        const float* wkv_i = wkv + (size_t)i*DM*2*DM;
        const float* wo_i  = wo  + (size_t)i*DM*DM;
        const float* bo_i  = bo  + (size_t)i*DM;
        const float* w1_i  = w1  + (size_t)i*DM*FFDIM;
        const float* b1_i  = b1  + (size_t)i*FFDIM;
        const float* w2_i  = w2  + (size_t)i*FFDIM*DM;
        const float* b2_i  = b2  + (size_t)i*DM;

        tcast_kernel<<<dim3(DM/32,    DM/32),    blk, 0, stream>>>(wq_i,  wt_qkv,         DM,    DM);
        tcast_kernel<<<dim3(2*DM/32,  DM/32),    blk, 0, stream>>>(wkv_i, wt_qkv + DM*DM, DM,    2*DM);
        tcast_kernel<<<dim3(DM/32,    DM/32),    blk, 0, stream>>>(wo_i,  wt_o,           DM,    DM);
        tcast_kernel<<<dim3(FFDIM/32, DM/32),    blk, 0, stream>>>(w1_i,  wt_1,           DM,    FFDIM);
        tcast_kernel<<<dim3(DM/32,    FFDIM/32), blk, 0, stream>>>(w2_i,  wt_2,           FFDIM, DM);

        // h = LN(x) -> bf16
        ln_kernel<true><<<MROWS, blk, 0, stream>>>(x, attg + (size_t)i*DM, attb + (size_t)i*DM, hbuf);
        // qkv = h @ [wq|wkv] + [bq|bkv] -> bf16
        gemm_bf16_kernel<false,false,true><<<g_qkv, blk, 0, stream>>>(
            hbuf, wt_qkv, qkv_b + (size_t)i*QSTR, nullptr, qkvbuf, QSTR, DM);
        // vt = V^T (once per layer)
        vtrans_kernel<<<g_vt, blk, 0, stream>>>(qkvbuf, vtbuf);
        // att = flash_attention(qkv, vt) -> bf16
        attn_kernel<<<g_at, blk, 0, stream>>>(qkvbuf, vtbuf, attbuf);
        // x = x + att @ wo + bo
        gemm_bf16_kernel<false,true,false><<<g_sq, blk, 0, stream>>>(
            attbuf, wt_o, bo_i, x, x, DM, DM);
        // h = LN(x) -> bf16
        ln_kernel<true><<<MROWS, blk, 0, stream>>>(x, ffng + (size_t)i*DM, ffnb + (size_t)i*DM, hbuf);
        // h1 = softplus(h @ w1 + b1) -> bf16
        gemm_bf16_kernel<true,false,true><<<g_ff, blk, 0, stream>>>(
            hbuf, wt_1, b1_i, nullptr, h1buf, FFDIM, DM);
        // x = x + h1 @ w2 + b2
        gemm_bf16_kernel<false,true,false><<<g_sq, blk, 0, stream>>>(
            h1buf, wt_2, b2_i, x, x, DM, FFDIM);
    }
    // out = LN(x) fp32, in-place on d_out
    ln_kernel<false><<<MROWS, blk, 0, stream>>>(x, fg, fb, x);
}